// Round 6
// baseline (295.342 us; speedup 1.0000x reference)
//
#include <hip/hip_runtime.h>
#include <hip/hip_bf16.h>
#include <math.h>

#define Kn 4
#define Mm 128
#define Dd 64
#define Tt 256
#define Nn 254        // T-2
#define Cc 512        // Kn*Mm
#define ZSTRIDE 16384 // D*T
#define LSZ 65536     // per-d 256x256 bf16 L (in ushorts)

// ws float offsets. zb bf16 [d][c][s] occupies [0, 4194304); Lb bf16 follows.
#define AMU0_OFF 4194304              // 64*65536
#define AMU1_OFF 4210688
#define PLD_OFF  4227072
#define LB_OFF   4227136              // bf16 L, 64*65536 ushorts

typedef __attribute__((ext_vector_type(8))) short short8;
typedef __attribute__((ext_vector_type(4))) float f32x4;

#define GLD16(g, l) __builtin_amdgcn_global_load_lds( \
    (const __attribute__((address_space(1))) void*)(g), \
    (__attribute__((address_space(3))) void*)(l), 16, 0, 0)

__device__ inline unsigned short f2b(float x) {
  __hip_bfloat16 h = __float2bfloat16(x);
  return *(unsigned short*)&h;
}

// ---------------- K1: fused (blocks 0..63: Cholesky per d) + (blocks 64+: zcast) ----
#define PB 32
#define PSTRIDE 260   // col-major P: banks (4c+r)%32 distinct over r

__global__ __launch_bounds__(256) void k_main(const float* __restrict__ z,
                                              const float* __restrict__ log_tau,
                                              float* __restrict__ ws,
                                              float* __restrict__ out) {
  const int tid = threadIdx.x;

  // declare P first so any clamped-row read stays inside the LDS allocation
  __shared__ float P[PB * PSTRIDE];   // col-major: P[c*PSTRIDE + r]
  __shared__ float g[256];
  __shared__ float a0s[256], a1s[256];
  __shared__ float rd_s[PB], logv[PB];
  __shared__ unsigned short Wb[PB * PB];   // bf16 inv(L11), row-major
  __shared__ float logtot;

  if (blockIdx.x >= 64) {
    // ---------- zcast path: z -> bf16 [d][c][s] + edge passthrough ----------
    int rid = (blockIdx.x - 64) * 4 + (tid >> 6);   // d*512 + c
    int lane = tid & 63;
    int dd = rid >> 9, cc = rid & 511;
    const float* zr = z + cc * ZSTRIDE + dd * Tt;
    unsigned short* zbr = (unsigned short*)ws + (dd * 512 + cc) * 256;
#pragma unroll
    for (int i = 0; i < 4; ++i) {
      int s = lane + i * 64;
      float v = (s < Nn) ? zr[1 + s] : 0.f;
      zbr[s] = f2b(v);
    }
    if (lane == 0) out[cc * ZSTRIDE + dd * Tt] = zr[0];
    if (lane == 1) out[cc * ZSTRIDE + dd * Tt + 255] = zr[255];
    return;
  }

  // ---------- Cholesky path ----------
  const int d = blockIdx.x;
  const int lane = tid & 63, w = tid >> 6;
  const int m16 = lane & 15, quad = lane >> 4;
  __hip_bfloat16* Lb = (__hip_bfloat16*)(ws + LB_OFF) + d * LSZ;
  const unsigned short* Lbu = (const unsigned short*)Lb;

  float tau = expf(log_tau[d]);
  float inv2 = 1.0f / (2.0f * tau * tau);
  float lf = (float)tid;
  g[tid] = expf(-(lf * lf) * inv2);
  if (tid == 0) logtot = 0.f;
  __syncthreads();
  {
    float b = g[255];
    float det = 1.0f - b * b;
    float a0 = 0.f, a1 = 0.f;
    if (tid < Nn) {
      float kp0 = g[tid + 1], kp1 = g[254 - tid];
      a0 = (kp0 - b * kp1) / det;
      a1 = (kp1 - b * kp0) / det;
    }
    a0s[tid] = a0; a1s[tid] = a1;
    ws[AMU0_OFF + d * 256 + tid] = a0;
    ws[AMU1_OFF + d * 256 + tid] = a1;
  }
  __syncthreads();

  for (int p = 0; p < 8; ++p) {
    const int j0 = p * PB;
    const int m = Nn - j0;
    const int bw = (m < PB) ? m : PB;

    // ---- slab build (Schur panel in MFMA-C layout) ----
    if (w * 64 < m) {
      f32x4 acc[4][2];
      // hoist per-column terms
      float e1g[2], e2g[2]; int scol[2];
#pragma unroll
      for (int tc = 0; tc < 2; ++tc) {
        int s = j0 + tc * 16 + m16;
        scol[tc] = s;
        int e1 = s + 1 > 255 ? 255 : s + 1;
        int e2 = 254 - s < 0 ? 0 : 254 - s;
        e1g[tc] = g[e1]; e2g[tc] = g[e2];
      }
#pragma unroll
      for (int ti = 0; ti < 4; ++ti) {
#pragma unroll
        for (int rg = 0; rg < 4; ++rg) {
          int rl = w * 64 + ti * 16 + quad * 4 + rg;
          float a0r = 0.f, a1r = 0.f; int t = j0 + rl;
          bool okr = (rl < m);
          if (okr) { a0r = a0s[t]; a1r = a1s[t]; }
#pragma unroll
          for (int tc = 0; tc < 2; ++tc) {
            float v = 0.f;
            if (okr) {
              float lagf = (float)(t - scol[tc]);
              v = __expf(-(lagf * lagf) * inv2) - a0r * e1g[tc] - a1r * e2g[tc];
              if (t == scol[tc]) v += 1e-5f;
            }
            acc[ti][tc][rg] = v;
          }
        }
      }
      // history: acc -= Lrows * Lcols^T over k = 0..j0 (B sign-negated)
      for (int kk = 0; kk < p; ++kk) {
        const int k0 = kk * 32;
        short8 bfr[2];
#pragma unroll
        for (int tc = 0; tc < 2; ++tc) {
          int row = j0 + tc * 16 + m16;        // <= 255
          union { short8 s; unsigned int u[4]; } nb;
          nb.s = *(const short8*)&Lbu[row * 256 + k0 + quad * 8];
          nb.u[0] ^= 0x80008000u; nb.u[1] ^= 0x80008000u;
          nb.u[2] ^= 0x80008000u; nb.u[3] ^= 0x80008000u;
          bfr[tc] = nb.s;
        }
        short8 afr[4];
#pragma unroll
        for (int ti = 0; ti < 4; ++ti) {
          int row = j0 + w * 64 + ti * 16 + m16;
          if (row > 255) row = 255;            // row 255 is all-zero
          afr[ti] = *(const short8*)&Lbu[row * 256 + k0 + quad * 8];
        }
#pragma unroll
        for (int ti = 0; ti < 4; ++ti)
#pragma unroll
          for (int tc = 0; tc < 2; ++tc)
            acc[ti][tc] = __builtin_amdgcn_mfma_f32_16x16x32_bf16(afr[ti], bfr[tc], acc[ti][tc], 0, 0, 0);
      }
      // dump slab to LDS panel (D layout: row = quad*4+rg, col = m16)
#pragma unroll
      for (int ti = 0; ti < 4; ++ti)
#pragma unroll
        for (int tc = 0; tc < 2; ++tc)
#pragma unroll
          for (int rg = 0; rg < 4; ++rg) {
            int rl = w * 64 + ti * 16 + quad * 4 + rg;
            if (rl < m) P[(tc * 16 + m16) * PSTRIDE + rl] = acc[ti][tc][rg];
          }
    }
    __syncthreads();

    // ---- wave0: register Cholesky of 32x32 diag + inv(L11) ----
    if (tid < PB) {
      const int r = tid;
      float a[PB];
#pragma unroll
      for (int c = 0; c < PB; ++c) a[c] = P[c * PSTRIDE + r];
      float dr = 1.0f;
#pragma unroll
      for (int j = 0; j < PB; ++j) {
        float pj = __shfl(a[j], j);
        if (r == j) dr = pj;
        float s = a[j] * (1.0f / pj);
#pragma unroll
        for (int k = j + 1; k < PB; ++k)
          a[k] -= s * __shfl(a[j], k);
      }
      float rinv = 1.0f / sqrtf(dr);
      rd_s[r] = rinv;
      logv[r] = (r < bw) ? 0.5f * logf(fabsf(dr)) : 0.f;
      // write true L11 into P (zeros above diag / invalid cols)
#pragma unroll
      for (int c = 0; c < PB; ++c) {
        float sc = __shfl(rinv, c);
        float v = 0.f;
        if (c < bw) {
          if (c < r)       v = a[c] * sc;
          else if (c == r) v = sqrtf(dr);
        }
        P[c * PSTRIDE + r] = v;
      }
      // ---- inv(L11), column-parallel (lane = column c) ----
      const int c = tid;
      float wv[PB];
#pragma unroll
      for (int rr2 = 0; rr2 < PB; ++rr2) wv[rr2] = (rr2 == c) ? rinv : 0.f;
      // note: wv[c] uses this lane's own rinv = 1/L[c][c]
#pragma unroll
      for (int r2 = 1; r2 < PB; ++r2) {
        float s2 = 0.f;
#pragma unroll
        for (int k = 0; k < r2; ++k)
          s2 += P[k * PSTRIDE + r2] * wv[k];   // broadcast L[r2][k]
        float rrv = rd_s[r2];
        if (c < r2) wv[r2] = -rrv * s2;
      }
#pragma unroll
      for (int r2 = 0; r2 < PB; ++r2)
        Wb[r2 * PB + c] = f2b(wv[r2]);
    }
    __syncthreads();
    if (tid == 0) {
      float s = logtot;
      for (int j2 = 0; j2 < bw; ++j2) s += logv[j2];
      logtot = s;
    }

    // ---- TRSM as MFMA: L21 = P21 * W^T ----
    const int nrows = m - bw;               // >0 only when bw==PB
    if (nrows > 0) {
      short8 bfr2[2];
#pragma unroll
      for (int tc = 0; tc < 2; ++tc)
        bfr2[tc] = *(const short8*)&Wb[(tc * 16 + m16) * PB + quad * 8];
      short8 afr2[4];
#pragma unroll
      for (int ti = 0; ti < 4; ++ti) {
        int ri = PB + w * 64 + ti * 16 + m16;
        if (ri >= m) ri = PB;                // clamp (junk rows discarded at dump)
        union { short8 s8; unsigned short us[8]; } uu;
#pragma unroll
        for (int q = 0; q < 8; ++q)
          uu.us[q] = f2b(P[(quad * 8 + q) * PSTRIDE + ri]);
        afr2[ti] = uu.s8;
      }
      f32x4 acc2[4][2];
#pragma unroll
      for (int ti = 0; ti < 4; ++ti)
#pragma unroll
        for (int tc = 0; tc < 2; ++tc)
          acc2[ti][tc] = (f32x4){0.f, 0.f, 0.f, 0.f};
#pragma unroll
      for (int ti = 0; ti < 4; ++ti)
#pragma unroll
        for (int tc = 0; tc < 2; ++tc)
          acc2[ti][tc] = __builtin_amdgcn_mfma_f32_16x16x32_bf16(afr2[ti], bfr2[tc], acc2[ti][tc], 0, 0, 0);
      // dump L21 into P rows PB+ro
#pragma unroll
      for (int ti = 0; ti < 4; ++ti)
#pragma unroll
        for (int tc = 0; tc < 2; ++tc)
#pragma unroll
          for (int rg = 0; rg < 4; ++rg) {
            int ro = w * 64 + ti * 16 + quad * 4 + rg;
            if (ro < nrows) P[(tc * 16 + m16) * PSTRIDE + PB + ro] = acc2[ti][tc][rg];
          }
    }
    __syncthreads();

    // ---- vectorized bf16 writeback of full 256-row stripe (cols j0..j0+31) ----
    {
      const int row = (tid >> 2);            // 0..63 within pass
      const int ch = tid & 3;                // 16B chunk (8 bf16)
#pragma unroll
      for (int pass = 0; pass < 4; ++pass) {
        int grow = pass * 64 + row;          // 0..255
        int rl = grow - j0;
        union { short8 s8; unsigned short us[8]; } uu;
        if (rl >= 0 && rl < m) {
#pragma unroll
          for (int q = 0; q < 8; ++q)
            uu.us[q] = f2b(P[(ch * 8 + q) * PSTRIDE + rl]);
        } else {
#pragma unroll
          for (int q = 0; q < 8; ++q) uu.us[q] = 0;
        }
        *(short8*)&Lbu[grow * 256 + j0 + ch * 8] = uu.s8;
      }
    }
    __syncthreads();   // drains Lb stores for next panel's history reads
  }
  if (tid == 0) ws[PLD_OFF + d] = logtot;
}

// ---------------- K2: logdet reduce + scalar output ----------------
__global__ void k_logdet(const float* __restrict__ ws, const float* __restrict__ sldj,
                         float* __restrict__ out) {
  int tid = threadIdx.x;  // 64 threads
  float v = ws[PLD_OFF + tid];
  for (int off = 32; off > 0; off >>= 1) v += __shfl_down(v, off);
  if (tid == 0) out[8388608] = sldj[0] + v;   // Cc*ZSTRIDE
}

// ---------------- K3: MFMA bf16 GEMM: out[c,1+t] = sum_s z[c,s]*L[t,s] + mu ----
__global__ __launch_bounds__(256) void k_gemm(const float* __restrict__ z,
                                              const float* __restrict__ ws,
                                              float* __restrict__ out) {
  const int d = blockIdx.z;
  const int t0 = blockIdx.y * 128;
  const int c0 = blockIdx.x * 128;
  const int tid = threadIdx.x;
  const unsigned short* zb = (const unsigned short*)ws + d * (512 * 256);
  const unsigned short* lb = (const unsigned short*)(ws + LB_OFF) + d * LSZ;
  __shared__ unsigned short As[128 * 32];   // [c][s] bf16
  __shared__ unsigned short Bs[128 * 32];   // [t][s] bf16
  f32x4 acc[4][4];
#pragma unroll
  for (int mi = 0; mi < 4; ++mi)
#pragma unroll
    for (int ni = 0; ni < 4; ++ni)
      acc[mi][ni] = (f32x4){0.f, 0.f, 0.f, 0.f};

  const int l = tid & 63, w = tid >> 6;
  const int wm = w & 1, wn = w >> 1;       // wave tile: c += wm*64, t += wn*64
  const int m16 = l & 15, quad = l >> 4;

  const int nks = (blockIdx.y == 0) ? 4 : 8;   // L[t<128][s>=128]==0 -> skip
  for (int ks = 0; ks < nks; ++ks) {
    const int s0 = ks * 32;
#pragma unroll
    for (int i = 0; i < 2; ++i) {
      int e = i * 256 + tid;
      int row = e >> 2, half = e & 3;      // 4x16B chunks per 32-bf16 row
      GLD16(zb + (c0 + row) * 256 + s0 + half * 8, &As[e * 8]);
      GLD16(lb + (t0 + row) * 256 + s0 + half * 8, &Bs[e * 8]);
    }
    __syncthreads();
    short8 af[4], bf[4];
#pragma unroll
    for (int mi = 0; mi < 4; ++mi)
      af[mi] = *(const short8*)&As[(wm * 64 + mi * 16 + m16) * 32 + quad * 8];
#pragma unroll
    for (int ni = 0; ni < 4; ++ni)
      bf[ni] = *(const short8*)&Bs[(wn * 64 + ni * 16 + m16) * 32 + quad * 8];
#pragma unroll
    for (int mi = 0; mi < 4; ++mi)
#pragma unroll
      for (int ni = 0; ni < 4; ++ni)
        acc[mi][ni] = __builtin_amdgcn_mfma_f32_16x16x32_bf16(af[mi], bf[ni], acc[mi][ni], 0, 0, 0);
    __syncthreads();
  }

  // epilogue: + Amu0[t]*z[c,0] + Amu1[t]*z[c,255]; store
  const float* Amu0 = ws + AMU0_OFF + d * 256;
  const float* Amu1 = ws + AMU1_OFF + d * 256;
  float a0v[4], a1v[4];
#pragma unroll
  for (int ni = 0; ni < 4; ++ni) {
    int t_ = t0 + wn * 64 + ni * 16 + m16;
    a0v[ni] = Amu0[t_]; a1v[ni] = Amu1[t_];
  }
#pragma unroll
  for (int mi = 0; mi < 4; ++mi) {
#pragma unroll
    for (int rg = 0; rg < 4; ++rg) {
      int c_ = c0 + wm * 64 + mi * 16 + quad * 4 + rg;
      const float* zc = z + c_ * ZSTRIDE + d * Tt;
      float z0 = zc[0], z1 = zc[255];
      float* op = out + c_ * ZSTRIDE + d * Tt + 1;
#pragma unroll
      for (int ni = 0; ni < 4; ++ni) {
        int t_ = t0 + wn * 64 + ni * 16 + m16;
        float v = acc[mi][ni][rg] + a0v[ni] * z0 + a1v[ni] * z1;
        if (t_ < Nn) op[t_] = v;
      }
    }
  }
}

extern "C" void kernel_launch(void* const* d_in, const int* in_sizes, int n_in,
                              void* d_out, int out_size, void* d_ws, size_t ws_size,
                              hipStream_t stream) {
  const float* z = (const float*)d_in[0];
  const float* sldj = (const float*)d_in[1];
  const float* log_tau = (const float*)d_in[2];
  float* out = (float*)d_out;
  float* ws = (float*)d_ws;

  hipLaunchKernelGGL(k_main, dim3(64 + 8192), dim3(256), 0, stream, z, log_tau, ws, out);
  hipLaunchKernelGGL(k_logdet, dim3(1), dim3(64), 0, stream, ws, sldj, out);
  hipLaunchKernelGGL(k_gemm, dim3(4, 2, Dd), dim3(256), 0, stream, z, ws, out);
}

// Round 7
// 295.299 us; speedup vs baseline: 1.0001x; 1.0001x over previous
//
#include <hip/hip_runtime.h>
#include <hip/hip_bf16.h>
#include <math.h>

#define Kn 4
#define Mm 128
#define Dd 64
#define Tt 256
#define Nn 254        // T-2
#define Cc 512        // Kn*Mm
#define ZSTRIDE 16384 // D*T
#define LSZ 65536     // per-d 256x256 bf16 L (in ushorts)

// ws float offsets. zb bf16 [d][c][s] occupies [0, 4194304); Lb bf16 follows.
#define AMU0_OFF 4194304              // 64*65536
#define AMU1_OFF 4210688
#define PLD_OFF  4227072
#define LB_OFF   4227136              // bf16 L, 64*65536 ushorts

typedef __attribute__((ext_vector_type(8))) short short8;
typedef __attribute__((ext_vector_type(4))) float f32x4;

#define GLD16(g, l) __builtin_amdgcn_global_load_lds( \
    (const __attribute__((address_space(1))) void*)(g), \
    (__attribute__((address_space(3))) void*)(l), 16, 0, 0)

__device__ inline unsigned short f2b(float x) {
  __hip_bfloat16 h = __float2bfloat16(x);
  return *(unsigned short*)&h;
}

// ---------------- K0: zero bf16 L buffer ----------------
__global__ __launch_bounds__(256) void k_zero(float* __restrict__ ws) {
  int i = (blockIdx.x * 256 + threadIdx.x) * 4;
  *(float4*)(ws + LB_OFF + i) = (float4){0.f, 0.f, 0.f, 0.f};
}

// ---------------- K1: z -> bf16 [d][c][s] + edge passthrough ----------------
__global__ __launch_bounds__(256) void k_zcast(const float* __restrict__ z,
                                               float* __restrict__ ws,
                                               float* __restrict__ out) {
  int rid = blockIdx.x * 4 + (threadIdx.x >> 6);   // 0..32767 = d*512 + c
  int lane = threadIdx.x & 63;
  int dd = rid >> 9, cc = rid & 511;
  const float* zr = z + cc * ZSTRIDE + dd * Tt;
  unsigned short* zbr = (unsigned short*)ws + (dd * 512 + cc) * 256;
#pragma unroll
  for (int i = 0; i < 4; ++i) {
    int s = lane + i * 64;
    float v = (s < Nn) ? zr[1 + s] : 0.f;
    zbr[s] = f2b(v);
  }
  if (lane == 0) out[cc * ZSTRIDE + dd * Tt] = zr[0];
  if (lane == 1) out[cc * ZSTRIDE + dd * Tt + 255] = zr[255];
}

// ---------------- K2: fused left-looking Cholesky, one block per d ----------------
// ROUND-5 frame (measured 119us) with ONE change: TRSM -> inv(L11) + MFMA.
#define PB 32
#define PSTRIDE 260   // col-major P: banks (4c+r)%32 distinct over r

__global__ __launch_bounds__(256) void k_chol(const float* __restrict__ log_tau,
                                              float* __restrict__ ws) {
  const int d = blockIdx.x;
  const int tid = threadIdx.x;
  const int lane = tid & 63, w = tid >> 6;
  const int m16 = lane & 15, quad = lane >> 4;
  __hip_bfloat16* Lb = (__hip_bfloat16*)(ws + LB_OFF) + d * LSZ;
  const unsigned short* Lbu = (const unsigned short*)Lb;
  __shared__ float P[PB * PSTRIDE];   // col-major: P[c*PSTRIDE + r]
  __shared__ float g[256];
  __shared__ float a0s[256], a1s[256];
  __shared__ float rd_s[PB], logv[PB];
  __shared__ unsigned short Wb[PB * PB];   // bf16 inv(L11), row-major
  __shared__ float logtot;

  float tau = expf(log_tau[d]);
  float inv2 = 1.0f / (2.0f * tau * tau);
  float lf = (float)tid;
  g[tid] = expf(-(lf * lf) * inv2);
  if (tid == 0) logtot = 0.f;
  __syncthreads();
  {
    float b = g[255];
    float det = 1.0f - b * b;
    float a0 = 0.f, a1 = 0.f;
    if (tid < Nn) {
      float kp0 = g[tid + 1], kp1 = g[254 - tid];
      a0 = (kp0 - b * kp1) / det;
      a1 = (kp1 - b * kp0) / det;
    }
    a0s[tid] = a0; a1s[tid] = a1;
    ws[AMU0_OFF + d * 256 + tid] = a0;
    ws[AMU1_OFF + d * 256 + tid] = a1;
  }
  __syncthreads();

  for (int p = 0; p < 8; ++p) {
    const int j0 = p * PB;
    const int m = Nn - j0;
    const int bw = (m < PB) ? m : PB;

    // ---- slab build (Schur panel in MFMA-C layout), round-5 g-table version ----
    if (w * 64 < m) {
      f32x4 acc[4][2];
#pragma unroll
      for (int ti = 0; ti < 4; ++ti)
#pragma unroll
        for (int tc = 0; tc < 2; ++tc) {
#pragma unroll
          for (int rg = 0; rg < 4; ++rg) {
            int rl = w * 64 + ti * 16 + quad * 4 + rg;
            float v = 0.f;
            if (rl < m) {
              int t = j0 + rl;                 // < Nn
              int s = j0 + tc * 16 + m16;      // <= 255 (junk cols ok)
              int lag = t - s; lag = lag < 0 ? -lag : lag;
              int e1 = s + 1 > 255 ? 255 : s + 1;
              int e2 = 254 - s < 0 ? 0 : 254 - s;
              v = g[lag] - a0s[t] * g[e1] - a1s[t] * g[e2];
              if (t == s) v += 1e-5f;
            }
            acc[ti][tc][rg] = v;
          }
        }
      // history: acc -= Lrows * Lcols^T over k = 0..j0 (B sign-negated)
      for (int kk = 0; kk < p; ++kk) {
        const int k0 = kk * 32;
        short8 bfr[2];
#pragma unroll
        for (int tc = 0; tc < 2; ++tc) {
          int row = j0 + tc * 16 + m16;        // <= 255
          union { short8 s; unsigned int u[4]; } nb;
          nb.s = *(const short8*)&Lbu[row * 256 + k0 + quad * 8];
          nb.u[0] ^= 0x80008000u; nb.u[1] ^= 0x80008000u;
          nb.u[2] ^= 0x80008000u; nb.u[3] ^= 0x80008000u;
          bfr[tc] = nb.s;
        }
        short8 afr[4];
#pragma unroll
        for (int ti = 0; ti < 4; ++ti) {
          int row = j0 + w * 64 + ti * 16 + m16;
          if (row > 255) row = 255;            // row 255 is all-zero
          afr[ti] = *(const short8*)&Lbu[row * 256 + k0 + quad * 8];
        }
#pragma unroll
        for (int ti = 0; ti < 4; ++ti)
#pragma unroll
          for (int tc = 0; tc < 2; ++tc)
            acc[ti][tc] = __builtin_amdgcn_mfma_f32_16x16x32_bf16(afr[ti], bfr[tc], acc[ti][tc], 0, 0, 0);
      }
      // dump slab to LDS panel (D layout: row = quad*4+rg, col = m16)
#pragma unroll
      for (int ti = 0; ti < 4; ++ti)
#pragma unroll
        for (int tc = 0; tc < 2; ++tc)
#pragma unroll
          for (int rg = 0; rg < 4; ++rg) {
            int rl = w * 64 + ti * 16 + quad * 4 + rg;
            if (rl < m) P[(tc * 16 + m16) * PSTRIDE + rl] = acc[ti][tc][rg];
          }
    }
    __syncthreads();

    // ---- wave0: register Cholesky of 32x32 diag + inv(L11) ----
    if (tid < PB) {
      const int r = tid;
      float a[PB];
#pragma unroll
      for (int c = 0; c < PB; ++c) a[c] = P[c * PSTRIDE + r];
      float dr = 1.0f;
#pragma unroll
      for (int j = 0; j < PB; ++j) {
        float pj = __shfl(a[j], j);
        if (r == j) dr = pj;
        float s = a[j] * (1.0f / pj);
#pragma unroll
        for (int k = j + 1; k < PB; ++k)
          a[k] -= s * __shfl(a[j], k);
      }
      float rinv = 1.0f / sqrtf(dr);
      rd_s[r] = rinv;
      logv[r] = (r < bw) ? 0.5f * logf(fabsf(dr)) : 0.f;
      // write true L11 into P (zeros above diag) + bf16 Lb row (round-5 store)
      if (r < m) {
        __hip_bfloat16* lbrow = Lb + (j0 + r) * 256 + j0;
#pragma unroll
        for (int c = 0; c < PB; ++c) {
          float sc = __shfl(rinv, c);
          float v = 0.f;
          if (c < bw) {
            if (c < r)       v = a[c] * sc;
            else if (c == r) v = sqrtf(dr);
          }
          P[c * PSTRIDE + r] = v;
          lbrow[c] = __float2bfloat16(v);
        }
      }
      // ---- inv(L11), column-parallel (lane = column c) ----
      const int c = tid;
      float wv[PB];
#pragma unroll
      for (int rr2 = 0; rr2 < PB; ++rr2) wv[rr2] = (rr2 == c) ? rinv : 0.f;
#pragma unroll
      for (int r2 = 1; r2 < PB; ++r2) {
        float s2 = 0.f;
#pragma unroll
        for (int k = 0; k < r2; ++k)
          s2 += P[k * PSTRIDE + r2] * wv[k];   // broadcast L[r2][k]
        float rrv = rd_s[r2];
        if (c < r2) wv[r2] = -rrv * s2;
      }
#pragma unroll
      for (int r2 = 0; r2 < PB; ++r2)
        Wb[r2 * PB + c] = f2b(wv[r2]);
    }
    __syncthreads();
    if (tid == 0) {
      float s = logtot;
      for (int j2 = 0; j2 < bw; ++j2) s += logv[j2];
      logtot = s;
    }

    // ---- TRSM as MFMA: L21 = P21 * W^T, store bf16 L21 directly ----
    const int nrows = m - bw;               // >0 only when bw==PB
    if (nrows > 0) {
      short8 bfr2[2];
#pragma unroll
      for (int tc = 0; tc < 2; ++tc)
        bfr2[tc] = *(const short8*)&Wb[(tc * 16 + m16) * PB + quad * 8];
      short8 afr2[4];
#pragma unroll
      for (int ti = 0; ti < 4; ++ti) {
        int ri = PB + w * 64 + ti * 16 + m16;
        if (ri >= m) ri = PB;                // clamp (junk rows discarded at store)
        union { short8 s8; unsigned short us[8]; } uu;
#pragma unroll
        for (int q = 0; q < 8; ++q)
          uu.us[q] = f2b(P[(quad * 8 + q) * PSTRIDE + ri]);
        afr2[ti] = uu.s8;
      }
      f32x4 acc2[4][2];
#pragma unroll
      for (int ti = 0; ti < 4; ++ti)
#pragma unroll
        for (int tc = 0; tc < 2; ++tc) {
          acc2[ti][tc] = (f32x4){0.f, 0.f, 0.f, 0.f};
          acc2[ti][tc] = __builtin_amdgcn_mfma_f32_16x16x32_bf16(afr2[ti], bfr2[tc], acc2[ti][tc], 0, 0, 0);
        }
      // store L21 rows (scattered 2B, round-5 volume)
#pragma unroll
      for (int ti = 0; ti < 4; ++ti)
#pragma unroll
        for (int tc = 0; tc < 2; ++tc)
#pragma unroll
          for (int rg = 0; rg < 4; ++rg) {
            int ro = w * 64 + ti * 16 + quad * 4 + rg;
            if (ro < nrows)
              Lb[(j0 + PB + ro) * 256 + j0 + tc * 16 + m16] = __float2bfloat16(acc2[ti][tc][rg]);
          }
    }
    __syncthreads();   // drains Lb stores for next panel's history reads
  }
  if (tid == 0) ws[PLD_OFF + d] = logtot;
}

// ---------------- K3: logdet reduce + scalar output ----------------
__global__ void k_logdet(const float* __restrict__ ws, const float* __restrict__ sldj,
                         float* __restrict__ out) {
  int tid = threadIdx.x;  // 64 threads
  float v = ws[PLD_OFF + tid];
  for (int off = 32; off > 0; off >>= 1) v += __shfl_down(v, off);
  if (tid == 0) out[8388608] = sldj[0] + v;   // Cc*ZSTRIDE
}

// ---------------- K4: MFMA bf16 GEMM: out[c,1+t] = sum_s z[c,s]*L[t,s] + mu ----
__global__ __launch_bounds__(256) void k_gemm(const float* __restrict__ z,
                                              const float* __restrict__ ws,
                                              float* __restrict__ out) {
  const int d = blockIdx.z;
  const int t0 = blockIdx.y * 128;
  const int c0 = blockIdx.x * 128;
  const int tid = threadIdx.x;
  const unsigned short* zb = (const unsigned short*)ws + d * (512 * 256);
  const unsigned short* lb = (const unsigned short*)(ws + LB_OFF) + d * LSZ;
  __shared__ unsigned short As[128 * 32];   // [c][s] bf16
  __shared__ unsigned short Bs[128 * 32];   // [t][s] bf16
  f32x4 acc[4][4];
#pragma unroll
  for (int mi = 0; mi < 4; ++mi)
#pragma unroll
    for (int ni = 0; ni < 4; ++ni)
      acc[mi][ni] = (f32x4){0.f, 0.f, 0.f, 0.f};

  const int l = tid & 63, w = tid >> 6;
  const int wm = w & 1, wn = w >> 1;       // wave tile: c += wm*64, t += wn*64
  const int m16 = l & 15, quad = l >> 4;

  const int nks = (blockIdx.y == 0) ? 4 : 8;   // L[t<128][s>=128]==0 -> skip
  for (int ks = 0; ks < nks; ++ks) {
    const int s0 = ks * 32;
#pragma unroll
    for (int i = 0; i < 2; ++i) {
      int e = i * 256 + tid;
      int row = e >> 2, half = e & 3;      // 4x16B chunks per 32-bf16 row
      GLD16(zb + (c0 + row) * 256 + s0 + half * 8, &As[e * 8]);
      GLD16(lb + (t0 + row) * 256 + s0 + half * 8, &Bs[e * 8]);
    }
    __syncthreads();
    short8 af[4], bf[4];
#pragma unroll
    for (int mi = 0; mi < 4; ++mi)
      af[mi] = *(const short8*)&As[(wm * 64 + mi * 16 + m16) * 32 + quad * 8];
#pragma unroll
    for (int ni = 0; ni < 4; ++ni)
      bf[ni] = *(const short8*)&Bs[(wn * 64 + ni * 16 + m16) * 32 + quad * 8];
#pragma unroll
    for (int mi = 0; mi < 4; ++mi)
#pragma unroll
      for (int ni = 0; ni < 4; ++ni)
        acc[mi][ni] = __builtin_amdgcn_mfma_f32_16x16x32_bf16(af[mi], bf[ni], acc[mi][ni], 0, 0, 0);
    __syncthreads();
  }

  // epilogue: + Amu0[t]*z[c,0] + Amu1[t]*z[c,255]; store
  const float* Amu0 = ws + AMU0_OFF + d * 256;
  const float* Amu1 = ws + AMU1_OFF + d * 256;
  float a0v[4], a1v[4];
#pragma unroll
  for (int ni = 0; ni < 4; ++ni) {
    int t_ = t0 + wn * 64 + ni * 16 + m16;
    a0v[ni] = Amu0[t_]; a1v[ni] = Amu1[t_];
  }
#pragma unroll
  for (int mi = 0; mi < 4; ++mi) {
#pragma unroll
    for (int rg = 0; rg < 4; ++rg) {
      int c_ = c0 + wm * 64 + mi * 16 + quad * 4 + rg;
      const float* zc = z + c_ * ZSTRIDE + d * Tt;
      float z0 = zc[0], z1 = zc[255];
      float* op = out + c_ * ZSTRIDE + d * Tt + 1;
#pragma unroll
      for (int ni = 0; ni < 4; ++ni) {
        int t_ = t0 + wn * 64 + ni * 16 + m16;
        float v = acc[mi][ni][rg] + a0v[ni] * z0 + a1v[ni] * z1;
        if (t_ < Nn) op[t_] = v;
      }
    }
  }
}

extern "C" void kernel_launch(void* const* d_in, const int* in_sizes, int n_in,
                              void* d_out, int out_size, void* d_ws, size_t ws_size,
                              hipStream_t stream) {
  const float* z = (const float*)d_in[0];
  const float* sldj = (const float*)d_in[1];
  const float* log_tau = (const float*)d_in[2];
  float* out = (float*)d_out;
  float* ws = (float*)d_ws;

  hipLaunchKernelGGL(k_zero, dim3(2048), dim3(256), 0, stream, ws);
  hipLaunchKernelGGL(k_zcast, dim3(8192), dim3(256), 0, stream, z, ws, out);
  hipLaunchKernelGGL(k_chol, dim3(Dd), dim3(256), 0, stream, log_tau, ws);
  hipLaunchKernelGGL(k_logdet, dim3(1), dim3(64), 0, stream, ws, sldj, out);
  hipLaunchKernelGGL(k_gemm, dim3(4, 2, Dd), dim3(256), 0, stream, z, ws, out);
}